// Round 2
// baseline (298.496 us; speedup 1.0000x reference)
//
#include <hip/hip_runtime.h>
#include <hip/hip_bf16.h>
#include <cstdint>
#include <cstddef>

#define NROWS 16384
#define DDIM  256
#define SPLITS 16
#define CPS   (NROWS / SPLITS)   // 1024 cols per split
#define TILES (CPS / 64)         // 16 tiles of 64 cols

typedef __attribute__((ext_vector_type(4))) float f32x4;
typedef __attribute__((ext_vector_type(4))) float fl4;
typedef __attribute__((ext_vector_type(4))) int   i32x4;
typedef __attribute__((ext_vector_type(8))) int   i32x8;

constexpr float SCALE_EXP2 = 20.609929155556627f; // log2(e)/0.07 folded into qn
constexpr float LN2F       = 0.69314718055994531f;
constexpr float INV_T      = 14.285714285714286f;

__device__ inline void gload_lds16(const void* g, void* l) {
  __builtin_amdgcn_global_load_lds(
      (const __attribute__((address_space(1))) void*)g,
      (__attribute__((address_space(3))) void*)l, 16, 0, 0);
}

// ---- kernel 1: normalize rows; qn = (q/||q||)*SCALE_EXP2 as fp8, kn = k/||k|| as fp8.
// Fused: diag[row] = fp32 dot(qn_row, kn_row)/T via LDS; zero rowsum + out.
__global__ void norm_kernel(const float* __restrict__ q, const float* __restrict__ k,
                            unsigned char* __restrict__ qn, unsigned char* __restrict__ kn,
                            float* __restrict__ diag, float* __restrict__ rowsum,
                            float* __restrict__ out)
{
  __shared__ float sh[4][DDIM];
  const int wave = threadIdx.x >> 6, lane = threadIdx.x & 63;
  const int r2 = blockIdx.x * 2;          // rows r2, r2+1 for both q and k
  const bool is_k = wave >= 2;
  const int row = r2 + (wave & 1);
  const float* src = (is_k ? k : q) + (size_t)row * DDIM;
  unsigned char* dst = (is_k ? kn : qn) + (size_t)row * DDIM;

  fl4 v = *(const fl4*)(src + lane * 4);
  float ss = v.x * v.x + v.y * v.y + v.z * v.z + v.w * v.w;
#pragma unroll
  for (int m = 1; m < 64; m <<= 1) ss += __shfl_xor(ss, m, 64);
  float scale = 1.0f / fmaxf(sqrtf(ss), 1e-12f);

  fl4 nv; nv.x = v.x * scale; nv.y = v.y * scale; nv.z = v.z * scale; nv.w = v.w * scale;
  *(fl4*)&sh[wave][lane * 4] = nv;        // fp32 normalized for the diag dot

  float os = is_k ? 1.0f : SCALE_EXP2;    // fold exp2-scale into q side
  int p = __builtin_amdgcn_cvt_pk_fp8_f32(nv.x * os, nv.y * os, 0, false);
  p     = __builtin_amdgcn_cvt_pk_fp8_f32(nv.z * os, nv.w * os, p, true);
  *(int*)(dst + lane * 4) = p;

  __syncthreads();
  if (wave < 2) {                          // diag for row r2+wave, fp32
    float s = 0.0f;
#pragma unroll
    for (int j = 0; j < 4; ++j) s += sh[wave][lane * 4 + j] * sh[2 + wave][lane * 4 + j];
#pragma unroll
    for (int m = 1; m < 64; m <<= 1) s += __shfl_xor(s, m, 64);
    if (lane == 0) diag[row] = s * INV_T;
  }
  if (threadIdx.x < 2) rowsum[r2 + threadIdx.x] = 0.0f;
  if (blockIdx.x == 0 && threadIdx.x == 0) out[0] = 0.0f;
}

// ---- kernel 2: rowsum[row] += sum over this split's cols of exp2(qn.kn)
// grid 1024 = 64 row-blocks x 16 col-splits; 4 waves x 64 rows; MX-fp8 K=128 MFMA.
__global__ __launch_bounds__(256, 4) void lse_kernel(
    const unsigned char* __restrict__ qn, const unsigned char* __restrict__ kn,
    float* __restrict__ rowsum)
{
  __shared__ __attribute__((aligned(16))) unsigned char Bs[64 * DDIM]; // 16 KB

  const int tid  = threadIdx.x;
  const int wave = tid >> 6, lane = tid & 63;
  const int l15  = lane & 15, quad = lane >> 4;
  const int split = blockIdx.x & (SPLITS - 1);
  const int rb    = blockIdx.x / SPLITS;
  const int wrow  = rb * 256 + wave * 64;
  const int col_base = split * CPS;

  // A fragments: 4 subtiles x 2 K-steps(128) x 32B/lane = 64 VGPRs.
  // Layout (16x16x128 f8f6f4): m = lane&15, k = quad*32 + j.
  i32x8 A[4][2];
#pragma unroll
  for (int s = 0; s < 4; ++s) {
    const unsigned char* ap = qn + (size_t)(wrow + s * 16 + l15) * DDIM + quad * 32;
#pragma unroll
    for (int ks = 0; ks < 2; ++ks)
      A[s][ks] = *(const i32x8*)(ap + ks * 128);
  }

  float sums[4][4];
#pragma unroll
  for (int s = 0; s < 4; ++s)
#pragma unroll
    for (int r = 0; r < 4; ++r) sums[s][r] = 0.0f;

  for (int ct = 0; ct < TILES; ++ct) {
    const unsigned char* kbase = kn + (size_t)(col_base + ct * 64) * DDIM;
    __syncthreads();
    // Stage 64 cols x 256B: 1024 16B chunks; slot jj of row n holds global
    // chunk j = jj ^ (n&15) (bank-conflict swizzle). LDS dest linear in tid
    // -> satisfies global_load_lds uniform-base + lane*16 rule.
#pragma unroll
    for (int i = 0; i < 4; ++i) {
      int L = i * 256 + tid;
      int n = L >> 4, jj = L & 15;
      int j = jj ^ (n & 15);
      gload_lds16(kbase + (size_t)n * DDIM + j * 16, (void*)(Bs + L * 16));
    }
    __syncthreads();

#pragma unroll
    for (int cs = 0; cs < 4; ++cs) {
      int n  = cs * 16 + l15;
      int nb = n & 15;
      const unsigned char* brow = Bs + n * DDIM;
      f32x4 acc0 = {0.f, 0.f, 0.f, 0.f};
      f32x4 acc1 = {0.f, 0.f, 0.f, 0.f};
      f32x4 acc2 = {0.f, 0.f, 0.f, 0.f};
      f32x4 acc3 = {0.f, 0.f, 0.f, 0.f};
#pragma unroll
      for (int ks = 0; ks < 2; ++ks) {
        int c0 = ks * 8 + quad * 2;
        i32x4 lo = *(const i32x4*)(brow + ((c0 ^ nb) * 16));
        i32x4 hi = *(const i32x4*)(brow + (((c0 + 1) ^ nb) * 16));
        i32x8 b = {lo.x, lo.y, lo.z, lo.w, hi.x, hi.y, hi.z, hi.w};
        acc0 = __builtin_amdgcn_mfma_scale_f32_16x16x128_f8f6f4(A[0][ks], b, acc0, 0, 0, 0, 127, 0, 127);
        acc1 = __builtin_amdgcn_mfma_scale_f32_16x16x128_f8f6f4(A[1][ks], b, acc1, 0, 0, 0, 127, 0, 127);
        acc2 = __builtin_amdgcn_mfma_scale_f32_16x16x128_f8f6f4(A[2][ks], b, acc2, 0, 0, 0, 127, 0, 127);
        acc3 = __builtin_amdgcn_mfma_scale_f32_16x16x128_f8f6f4(A[3][ks], b, acc3, 0, 0, 0, 127, 0, 127);
      }
      // C/D: col = lane&15, row = quad*4 + r. qn pre-scaled -> exp2 directly.
#pragma unroll
      for (int r = 0; r < 4; ++r) {
        sums[0][r] += __builtin_amdgcn_exp2f(acc0[r]);
        sums[1][r] += __builtin_amdgcn_exp2f(acc1[r]);
        sums[2][r] += __builtin_amdgcn_exp2f(acc2[r]);
        sums[3][r] += __builtin_amdgcn_exp2f(acc3[r]);
      }
    }
  }

#pragma unroll
  for (int s = 0; s < 4; ++s)
#pragma unroll
    for (int r = 0; r < 4; ++r) {
      float v = sums[s][r];
      v += __shfl_xor(v, 1, 64);
      v += __shfl_xor(v, 2, 64);
      v += __shfl_xor(v, 4, 64);
      v += __shfl_xor(v, 8, 64);
      if (l15 == 0) atomicAdd(&rowsum[wrow + s * 16 + quad * 4 + r], v);
    }
}

// ---- kernel 3: out = mean(ln(rowsum) - diag)
__global__ void final_kernel(const float* __restrict__ rowsum,
                             const float* __restrict__ diag,
                             float* __restrict__ out)
{
  int row = blockIdx.x * 256 + threadIdx.x;
  float c = __builtin_amdgcn_logf(rowsum[row]) * LN2F - diag[row];
#pragma unroll
  for (int m = 1; m < 64; m <<= 1) c += __shfl_xor(c, m, 64);
  __shared__ float red[4];
  int wave = threadIdx.x >> 6, lane = threadIdx.x & 63;
  if (lane == 0) red[wave] = c;
  __syncthreads();
  if (threadIdx.x == 0) {
    float s = red[0] + red[1] + red[2] + red[3];
    atomicAdd(out, s * (1.0f / NROWS));
  }
}

extern "C" void kernel_launch(void* const* d_in, const int* in_sizes, int n_in,
                              void* d_out, int out_size, void* d_ws, size_t ws_size,
                              hipStream_t stream)
{
  const float* q = (const float*)d_in[0];
  const float* k = (const float*)d_in[1];
  float* out = (float*)d_out;

  char* ws = (char*)d_ws;
  unsigned char* qn = (unsigned char*)ws;                    // 4 MB
  unsigned char* kn = (unsigned char*)(ws + (4u << 20));     // 4 MB
  float* diag   = (float*)(ws + (8u << 20));                 // 64 KB
  float* rowsum = (float*)(ws + (8u << 20) + (64u << 10));   // 64 KB

  norm_kernel <<<NROWS / 2, 256, 0, stream>>>(q, k, qn, kn, diag, rowsum, out);
  lse_kernel  <<<(NROWS / 256) * SPLITS, 256, 0, stream>>>(qn, kn, rowsum);
  final_kernel<<<NROWS / 256, 256, 0, stream>>>(rowsum, diag, out);
}

// Round 3
// 174.798 us; speedup vs baseline: 1.7077x; 1.7077x over previous
//
#include <hip/hip_runtime.h>
#include <hip/hip_bf16.h>
#include <cstdint>
#include <cstddef>

#define NROWS 16384
#define DDIM  256
#define SPLITS 12                 // 64 row-blocks x 12 col-splits = 768 blocks = 3/CU
#define NTILES 256                // 16384 cols / 64

typedef __attribute__((ext_vector_type(4))) float f32x4;
typedef __attribute__((ext_vector_type(4))) float fl4;
typedef __attribute__((ext_vector_type(4))) int   i32x4;
typedef __attribute__((ext_vector_type(8))) int   i32x8;

constexpr float SCALE_EXP2 = 20.609929155556627f; // log2(e)/0.07 folded into qn
constexpr float LN2F       = 0.69314718055994531f;
constexpr float INV_T      = 14.285714285714286f;

__device__ inline void gload_lds16(const void* g, void* l) {
  __builtin_amdgcn_global_load_lds(
      (const __attribute__((address_space(1))) void*)g,
      (__attribute__((address_space(3))) void*)l, 16, 0, 0);
}

// ---- kernel 1: normalize rows; qn = (q/||q||)*SCALE_EXP2 as fp8, kn = k/||k|| as fp8.
// Fused: diag[row] = fp32 dot of normalized rows / T; zero rowsum + out.
__global__ void norm_kernel(const float* __restrict__ q, const float* __restrict__ k,
                            unsigned char* __restrict__ qn, unsigned char* __restrict__ kn,
                            float* __restrict__ diag, float* __restrict__ rowsum,
                            float* __restrict__ out)
{
  __shared__ float sh[4][DDIM];
  const int wave = threadIdx.x >> 6, lane = threadIdx.x & 63;
  const int r2 = blockIdx.x * 2;
  const bool is_k = wave >= 2;
  const int row = r2 + (wave & 1);
  const float* src = (is_k ? k : q) + (size_t)row * DDIM;
  unsigned char* dst = (is_k ? kn : qn) + (size_t)row * DDIM;

  fl4 v = *(const fl4*)(src + lane * 4);
  float ss = v.x * v.x + v.y * v.y + v.z * v.z + v.w * v.w;
#pragma unroll
  for (int m = 1; m < 64; m <<= 1) ss += __shfl_xor(ss, m, 64);
  float scale = 1.0f / fmaxf(sqrtf(ss), 1e-12f);

  fl4 nv; nv.x = v.x * scale; nv.y = v.y * scale; nv.z = v.z * scale; nv.w = v.w * scale;
  *(fl4*)&sh[wave][lane * 4] = nv;

  float os = is_k ? 1.0f : SCALE_EXP2;
  int p = __builtin_amdgcn_cvt_pk_fp8_f32(nv.x * os, nv.y * os, 0, false);
  p     = __builtin_amdgcn_cvt_pk_fp8_f32(nv.z * os, nv.w * os, p, true);
  *(int*)(dst + lane * 4) = p;

  __syncthreads();
  if (wave < 2) {
    float s = 0.0f;
#pragma unroll
    for (int j = 0; j < 4; ++j) s += sh[wave][lane * 4 + j] * sh[2 + wave][lane * 4 + j];
#pragma unroll
    for (int m = 1; m < 64; m <<= 1) s += __shfl_xor(s, m, 64);
    if (lane == 0) diag[row] = s * INV_T;
  }
  if (threadIdx.x < 2) rowsum[r2 + threadIdx.x] = 0.0f;
  if (blockIdx.x == 0 && threadIdx.x == 0) out[0] = 0.0f;
}

// ---- kernel 2: rowsum[row] += sum over this split's col-tiles of exp2(qn.kn)
// grid 768 = 64 row-blocks x 12 splits (uneven tile ranges). 4 waves x 64 rows.
// launch_bounds(256,3): VGPR cap ~170 -> A-hoard (64 VGPR) stays resident (R2 spilled at cap 128).
__global__ __launch_bounds__(256, 3) void lse_kernel(
    const unsigned char* __restrict__ qn, const unsigned char* __restrict__ kn,
    float* __restrict__ rowsum)
{
  __shared__ __attribute__((aligned(16))) unsigned char Bs[64 * DDIM]; // 16 KB

  const int tid  = threadIdx.x;
  const int wave = tid >> 6, lane = tid & 63;
  const int l15  = lane & 15, quad = lane >> 4;
  const int split = blockIdx.x % SPLITS;
  const int rb    = blockIdx.x / SPLITS;
  const int wrow  = rb * 256 + wave * 64;
  const int t0 = (split * NTILES) / SPLITS;
  const int t1 = ((split + 1) * NTILES) / SPLITS;

  // A fragments: 4 subtiles x 2 K-steps(128) x 32B/lane = 64 VGPRs.
  // Layout (16x16x128 f8f6f4): m = lane&15, k = quad*32 + j.
  i32x8 A[4][2];
#pragma unroll
  for (int s = 0; s < 4; ++s) {
    const unsigned char* ap = qn + (size_t)(wrow + s * 16 + l15) * DDIM + quad * 32;
#pragma unroll
    for (int ks = 0; ks < 2; ++ks)
      A[s][ks] = *(const i32x8*)(ap + ks * 128);
  }

  float sums[4][4];
#pragma unroll
  for (int s = 0; s < 4; ++s)
#pragma unroll
    for (int r = 0; r < 4; ++r) sums[s][r] = 0.0f;

  for (int ct = t0; ct < t1; ++ct) {
    const unsigned char* kbase = kn + (size_t)ct * 64 * DDIM;
    __syncthreads();
    // Stage 64 cols x 256B = 1024 16B chunks; slot jj of row n holds global
    // chunk j = jj ^ (n&15). LDS dest linear in tid (uniform base + lane*16).
#pragma unroll
    for (int i = 0; i < 4; ++i) {
      int L = i * 256 + tid;
      int n = L >> 4, jj = L & 15;
      int j = jj ^ (n & 15);
      gload_lds16(kbase + (size_t)n * DDIM + j * 16, (void*)(Bs + L * 16));
    }
    __syncthreads();

#pragma unroll
    for (int cs = 0; cs < 4; ++cs) {
      int n  = cs * 16 + l15;
      int nb = n & 15;
      const unsigned char* brow = Bs + n * DDIM;
      f32x4 acc0 = {0.f, 0.f, 0.f, 0.f};
      f32x4 acc1 = {0.f, 0.f, 0.f, 0.f};
      f32x4 acc2 = {0.f, 0.f, 0.f, 0.f};
      f32x4 acc3 = {0.f, 0.f, 0.f, 0.f};
#pragma unroll
      for (int ks = 0; ks < 2; ++ks) {
        int c0 = ks * 8 + quad * 2;
        i32x4 lo = *(const i32x4*)(brow + ((c0 ^ nb) * 16));
        i32x4 hi = *(const i32x4*)(brow + (((c0 + 1) ^ nb) * 16));
        i32x8 b = {lo.x, lo.y, lo.z, lo.w, hi.x, hi.y, hi.z, hi.w};
        acc0 = __builtin_amdgcn_mfma_scale_f32_16x16x128_f8f6f4(A[0][ks], b, acc0, 0, 0, 0, 127, 0, 127);
        acc1 = __builtin_amdgcn_mfma_scale_f32_16x16x128_f8f6f4(A[1][ks], b, acc1, 0, 0, 0, 127, 0, 127);
        acc2 = __builtin_amdgcn_mfma_scale_f32_16x16x128_f8f6f4(A[2][ks], b, acc2, 0, 0, 0, 127, 0, 127);
        acc3 = __builtin_amdgcn_mfma_scale_f32_16x16x128_f8f6f4(A[3][ks], b, acc3, 0, 0, 0, 127, 0, 127);
      }
      // C/D: col = lane&15, row = quad*4 + r. qn pre-scaled -> exp2 directly.
#pragma unroll
      for (int r = 0; r < 4; ++r) {
        sums[0][r] += __builtin_amdgcn_exp2f(acc0[r]);
        sums[1][r] += __builtin_amdgcn_exp2f(acc1[r]);
        sums[2][r] += __builtin_amdgcn_exp2f(acc2[r]);
        sums[3][r] += __builtin_amdgcn_exp2f(acc3[r]);
      }
    }
  }

#pragma unroll
  for (int s = 0; s < 4; ++s)
#pragma unroll
    for (int r = 0; r < 4; ++r) {
      float v = sums[s][r];
      v += __shfl_xor(v, 1, 64);
      v += __shfl_xor(v, 2, 64);
      v += __shfl_xor(v, 4, 64);
      v += __shfl_xor(v, 8, 64);
      if (l15 == 0) atomicAdd(&rowsum[wrow + s * 16 + quad * 4 + r], v);
    }
}

// ---- kernel 3: out = mean(ln(rowsum) - diag)
__global__ void final_kernel(const float* __restrict__ rowsum,
                             const float* __restrict__ diag,
                             float* __restrict__ out)
{
  int row = blockIdx.x * 256 + threadIdx.x;
  float c = __builtin_amdgcn_logf(rowsum[row]) * LN2F - diag[row];
#pragma unroll
  for (int m = 1; m < 64; m <<= 1) c += __shfl_xor(c, m, 64);
  __shared__ float red[4];
  int wave = threadIdx.x >> 6, lane = threadIdx.x & 63;
  if (lane == 0) red[wave] = c;
  __syncthreads();
  if (threadIdx.x == 0) {
    float s = red[0] + red[1] + red[2] + red[3];
    atomicAdd(out, s * (1.0f / NROWS));
  }
}

extern "C" void kernel_launch(void* const* d_in, const int* in_sizes, int n_in,
                              void* d_out, int out_size, void* d_ws, size_t ws_size,
                              hipStream_t stream)
{
  const float* q = (const float*)d_in[0];
  const float* k = (const float*)d_in[1];
  float* out = (float*)d_out;

  char* ws = (char*)d_ws;
  unsigned char* qn = (unsigned char*)ws;                    // 4 MB
  unsigned char* kn = (unsigned char*)(ws + (4u << 20));     // 4 MB
  float* diag   = (float*)(ws + (8u << 20));                 // 64 KB
  float* rowsum = (float*)(ws + (8u << 20) + (64u << 10));   // 64 KB

  norm_kernel <<<NROWS / 2, 256, 0, stream>>>(q, k, qn, kn, diag, rowsum, out);
  lse_kernel  <<<(NROWS / 256) * SPLITS, 256, 0, stream>>>(qn, kn, rowsum);
  final_kernel<<<NROWS / 256, 256, 0, stream>>>(rowsum, diag, out);
}